// Round 7
// baseline (412.239 us; speedup 1.0000x reference)
//
#include <hip/hip_runtime.h>
#include <math.h>

// Planar normalizing flow, B=524288 rows, D=64, F=32.
// Round-6 structure (3-phase small-state: c=x.W^T -> h recurrence -> z=x+U^T h,
// params wave-uniform s_loads) was latency-bound on the ~20KB/row param
// s_load stream (VALUBusy 30%, occ 29%, 135us). This round: R=4 register
// row-blocking. Each thread handles 4 rows strided by 256 (per-load
// coalescing pattern unchanged); every param s_load is shared by 4 rows'
// FMA chains (4x less param issue/latency per row) and phase B's serial
// tanh recurrence gets 4-way ILP. Phase B fully unrolled (static reg
// indexing); phase A/C dc-loops stay dynamic to cap code size.

#define NF_D 64
#define NF_F 32
#define RB 4            // rows per thread

typedef float f4 __attribute__((ext_vector_type(4)));

// ws layout (floats): uhat[32][64] | wuh[32] | wt[64][32] | Gt[32][32]
#define WS_UHAT 0
#define WS_WUH  (NF_F * NF_D)
#define WS_WT   (WS_WUH + NF_F)
#define WS_GT   (WS_WT + NF_D * NF_F)

// --- precompute: u_hat, wuh, W^T, G -------------------------------------
__global__ void nf_precompute(const float* __restrict__ us,
                              const float* __restrict__ ws,
                              float* __restrict__ wsbuf) {
  __shared__ float s_u[NF_F][NF_D];
  float* uhat = wsbuf + WS_UHAT;
  float* wuh  = wsbuf + WS_WUH;
  float* wt   = wsbuf + WS_WT;
  float* Gt   = wsbuf + WS_GT;
  int t = threadIdx.x;
  if (t < NF_F) {
    const float* u = us + t * NF_D;
    const float* w = ws + t * NF_D;
    float wu = 0.f, n2 = 0.f;
    for (int d = 0; d < NF_D; ++d) {
      wu = fmaf(u[d], w[d], wu);
      n2 = fmaf(w[d], w[d], n2);
    }
    float sp = fmaxf(wu, 0.f) + log1pf(expf(-fabsf(wu)));  // softplus
    float coef = (sp - 1.f - wu) / sqrtf(n2);
    for (int d = 0; d < NF_D; ++d) {
      float uh = fmaf(coef, w[d], u[d]);
      s_u[t][d] = uh;
      uhat[t * NF_D + d] = uh;
    }
    wuh[t] = fmaf(coef, n2, wu);         // w_t . u_hat_t
  }
  __syncthreads();
  for (int i = t; i < NF_D * NF_F; i += 256) {   // wt[d][f] = ws[f][d]
    int d = i / NF_F, f = i % NF_F;
    wt[i] = ws[f * NF_D + d];
  }
  for (int i = t; i < NF_F * NF_F; i += 256) {   // Gt[f][g] = u_hat_g . w_f
    int f = i / NF_F, g = i % NF_F;
    float s = 0.f;
    if (g < f) {
      const float* w = ws + f * NF_D;
      for (int d = 0; d < NF_D; ++d) s = fmaf(s_u[g][d], w[d], s);
    }
    Gt[i] = s;                                   // zero-padded for g >= f
  }
}

// tanh(x) = 1 - 2/(e^{2x}+1); hardware exp2/rcp; saturates to +-1.
__device__ __forceinline__ float fast_tanh(float x) {
  float e = __builtin_amdgcn_exp2f(x * 2.885390081777927f); // 2*log2(e)
  return 1.f - 2.f * __builtin_amdgcn_rcpf(e + 1.f);
}

// --- main: 4 rows per thread, three small-state phases -------------------
__global__ __launch_bounds__(256) void nf_main(
    const float* __restrict__ x,
    const float* __restrict__ bs,
    const float* __restrict__ wsbuf,
    float* __restrict__ out_z,
    float* __restrict__ out_ld,
    int B) {
  const float* __restrict__ uhat = wsbuf + WS_UHAT;
  const float* __restrict__ wuh  = wsbuf + WS_WUH;
  const float* __restrict__ wt   = wsbuf + WS_WT;
  const float* __restrict__ Gt   = wsbuf + WS_GT;

  // rows handled: base + 256*r  (consecutive lanes -> consecutive rows)
  int base = blockIdx.x * (256 * RB) + threadIdx.x;
  int rows[RB];
  bool ok[RB];
  #pragma unroll
  for (int r = 0; r < RB; ++r) {
    rows[r] = base + 256 * r;
    ok[r] = rows[r] < B;
    if (!ok[r]) rows[r] = 0;          // clamp (loads safe, stores skipped)
  }
  const f4* __restrict__ xv[RB];
  #pragma unroll
  for (int r = 0; r < RB; ++r)
    xv[r] = reinterpret_cast<const f4*>(x + (size_t)rows[r] * NF_D);

  // ---- Phase A: c[r][f] = x_r . w_f (transposed wt, uniform s_loads) ---
  f4 c[RB][NF_F / 4];
  #pragma unroll
  for (int r = 0; r < RB; ++r)
    #pragma unroll
    for (int q = 0; q < NF_F / 4; ++q) c[r][q] = (f4)(0.f);

  for (int dc = 0; dc < NF_D / 4; ++dc) {        // dynamic: code size
    f4 xd[RB];
    #pragma unroll
    for (int r = 0; r < RB; ++r) xd[r] = xv[r][dc];
    #pragma unroll
    for (int j = 0; j < 4; ++j) {
      const f4* __restrict__ wr =
          reinterpret_cast<const f4*>(wt + (dc * 4 + j) * NF_F);
      #pragma unroll
      for (int q = 0; q < NF_F / 4; ++q) {
        f4 wq_ = wr[q];                          // shared by 4 rows
        #pragma unroll
        for (int r = 0; r < RB; ++r)
          c[r][q] += wq_ * xd[r][j];
      }
    }
  }

  // ---- Phase B: recurrence, h[f] overwrites c[f]; 4 independent chains -
  float ldp[RB];
  #pragma unroll
  for (int r = 0; r < RB; ++r) ldp[r] = 1.f;
  #pragma unroll
  for (int f = 0; f < NF_F; ++f) {
    const f4* __restrict__ g4 = reinterpret_cast<const f4*>(Gt + f * NF_F);
    float b_f = bs[f], wuh_f = wuh[f];
    #pragma unroll
    for (int r = 0; r < RB; ++r) {
      f4 a = (f4)(0.f);
      #pragma unroll
      for (int q = 0; q < (f + 3) / 4; ++q)      // zero-padded triangular
        a += g4[q] * c[r][q];
      float s = c[r][f / 4][f % 4] + b_f + ((a.x + a.y) + (a.z + a.w));
      float hf = fast_tanh(s);
      float hp = fmaf(-hf, hf, 1.f);             // 1 - h^2
      ldp[r] *= fmaf(hp, wuh_f, 1.f);            // 1 + h'*(w.u_hat)
      c[r][f / 4][f % 4] = hf;                   // h replaces c
    }
  }

  // ---- Phase C: z = x + U_hat^T h, f4 chunks ---------------------------
  f4* __restrict__ ov[RB];
  #pragma unroll
  for (int r = 0; r < RB; ++r)
    ov[r] = reinterpret_cast<f4*>(out_z + (size_t)rows[r] * NF_D);

  for (int dc = 0; dc < NF_D / 4; ++dc) {        // dynamic: code size
    f4 acc[RB];
    #pragma unroll
    for (int r = 0; r < RB; ++r) acc[r] = xv[r][dc];   // x re-read: LLC
    #pragma unroll
    for (int f = 0; f < NF_F; ++f) {
      f4 uq = *reinterpret_cast<const f4*>(uhat + f * NF_D + dc * 4);
      #pragma unroll
      for (int r = 0; r < RB; ++r)
        acc[r] += uq * c[r][f / 4][f % 4];
    }
    #pragma unroll
    for (int r = 0; r < RB; ++r)
      if (ok[r]) ov[r][dc] = acc[r];
  }
  #pragma unroll
  for (int r = 0; r < RB; ++r)
    if (ok[r])
      out_ld[rows[r]] =
          __builtin_amdgcn_logf(fabsf(ldp[r])) * 0.6931471805599453f;
}

extern "C" void kernel_launch(void* const* d_in, const int* in_sizes, int n_in,
                              void* d_out, int out_size, void* d_ws, size_t ws_size,
                              hipStream_t stream) {
  const float* x    = (const float*)d_in[0];
  const float* us   = (const float*)d_in[1];
  const float* ws_p = (const float*)d_in[2];
  const float* bs   = (const float*)d_in[3];
  const int B = in_sizes[0] / NF_D;

  float* wsbuf = (float*)d_ws;   // 5152 floats ~ 20.6 KB
  float* out   = (float*)d_out;  // z [B*D] then sum_log_det [B]

  nf_precompute<<<1, 256, 0, stream>>>(us, ws_p, wsbuf);
  const int block = 256;
  const int rows_per_block = block * RB;
  const int grid = (B + rows_per_block - 1) / rows_per_block;
  nf_main<<<grid, block, 0, stream>>>(x, bs, wsbuf,
                                      out, out + (size_t)B * NF_D, B);
}

// Round 8
// 215.009 us; speedup vs baseline: 1.9173x; 1.9173x over previous
//
#include <hip/hip_runtime.h>
#include <math.h>

// Planar normalizing flow, B=524288 rows, D=64, F=32.
// 3-phase small-state per row: c = x.W^T -> triangular h recurrence ->
// z = x + Uhat^T h. Round 6 (s_load params, RB=1): 135us, VALUBusy 30% --
// stalled on SGPR-constrained param stream (~2 loads in flight max).
// Round 7 (RB=4): VGPR 256 + spill (FETCH 808MB), 412us.
// This round: RB=2 rows/thread + ALL params staged in LDS once per block.
// Uniform-address ds_read_b128 broadcasts are conflict-free and stage into
// VGPRs -> deep pipelining, no SGPR ceiling. State c[2][8]f4 = 64 VGPR.

#define NF_D 64
#define NF_F 32

typedef float f4 __attribute__((ext_vector_type(4)));

// wsbuf/LDS layout (floats):
//   [0,2048)    wt[d][f]   (d-major rows of 32)
//   [2048,3072) Gt[f][g]   (zero-padded triangular: g>=f is 0)
//   [3072,5120) uhat[f][d]
//   [5120,5152) wuh[f]
//   [5152,5184) bs[f]      (copied in main kernel from input)
#define L_WT   0
#define L_GT   2048
#define L_UH   3072
#define L_WUH  5120
#define L_BS   5152
#define L_TOT  5184

// --- precompute: u_hat, wuh, W^T, G -------------------------------------
__global__ void nf_precompute(const float* __restrict__ us,
                              const float* __restrict__ ws,
                              float* __restrict__ wsbuf) {
  __shared__ float s_u[NF_F][NF_D];
  int t = threadIdx.x;
  if (t < NF_F) {
    const float* u = us + t * NF_D;
    const float* w = ws + t * NF_D;
    float wu = 0.f, n2 = 0.f;
    for (int d = 0; d < NF_D; ++d) {
      wu = fmaf(u[d], w[d], wu);
      n2 = fmaf(w[d], w[d], n2);
    }
    float sp = fmaxf(wu, 0.f) + log1pf(expf(-fabsf(wu)));  // softplus
    float coef = (sp - 1.f - wu) / sqrtf(n2);
    for (int d = 0; d < NF_D; ++d) {
      float uh = fmaf(coef, w[d], u[d]);
      s_u[t][d] = uh;
      wsbuf[L_UH + t * NF_D + d] = uh;
    }
    wsbuf[L_WUH + t] = fmaf(coef, n2, wu);       // w_t . u_hat_t
  }
  __syncthreads();
  for (int i = t; i < NF_D * NF_F; i += 256) {   // wt[d][f] = ws[f][d]
    int d = i / NF_F, f = i % NF_F;
    wsbuf[L_WT + i] = ws[f * NF_D + d];
  }
  for (int i = t; i < NF_F * NF_F; i += 256) {   // Gt[f][g] = u_hat_g . w_f
    int f = i / NF_F, g = i % NF_F;
    float s = 0.f;
    if (g < f) {
      const float* w = ws + f * NF_D;
      for (int d = 0; d < NF_D; ++d) s = fmaf(s_u[g][d], w[d], s);
    }
    wsbuf[L_GT + i] = s;                         // zero-padded for g >= f
  }
}

// tanh(x) = 1 - 2/(e^{2x}+1); hardware exp2/rcp; saturates to +-1.
__device__ __forceinline__ float fast_tanh(float x) {
  float e = __builtin_amdgcn_exp2f(x * 2.885390081777927f); // 2*log2(e)
  return 1.f - 2.f * __builtin_amdgcn_rcpf(e + 1.f);
}

// --- main: 2 rows per thread, params in LDS ------------------------------
__global__ __launch_bounds__(256) void nf_main(
    const float* __restrict__ x,
    const float* __restrict__ bs,
    const float* __restrict__ wsbuf,
    float* __restrict__ out_z,
    float* __restrict__ out_ld,
    int B) {
  __shared__ float sp[L_TOT];
  for (int i = threadIdx.x; i < L_TOT - NF_F; i += 256) sp[i] = wsbuf[i];
  if (threadIdx.x < NF_F) sp[L_BS + threadIdx.x] = bs[threadIdx.x];
  __syncthreads();

  const f4* __restrict__ wt4 = reinterpret_cast<const f4*>(sp + L_WT);
  const f4* __restrict__ gt4 = reinterpret_cast<const f4*>(sp + L_GT);
  const f4* __restrict__ uh4 = reinterpret_cast<const f4*>(sp + L_UH);

  int t0 = blockIdx.x * 512 + threadIdx.x;     // row 0
  int t1 = t0 + 256;                           // row 1
  bool ok0 = t0 < B, ok1 = t1 < B;
  int r0 = ok0 ? t0 : 0, r1 = ok1 ? t1 : 0;

  const f4* __restrict__ xv0 = reinterpret_cast<const f4*>(x + (size_t)r0 * NF_D);
  const f4* __restrict__ xv1 = reinterpret_cast<const f4*>(x + (size_t)r1 * NF_D);

  // ---- Phase A: c[r][f] = x_r . w_f (LDS broadcast params) -------------
  f4 c0[NF_F / 4], c1[NF_F / 4];
  #pragma unroll
  for (int q = 0; q < NF_F / 4; ++q) { c0[q] = (f4)(0.f); c1[q] = (f4)(0.f); }

  #pragma unroll 2
  for (int dc = 0; dc < NF_D / 4; ++dc) {
    f4 a = xv0[dc], b = xv1[dc];
    #pragma unroll
    for (int j = 0; j < 4; ++j) {
      const f4* __restrict__ wr = wt4 + (dc * 4 + j) * (NF_F / 4);
      #pragma unroll
      for (int q = 0; q < NF_F / 4; ++q) {
        f4 wv = wr[q];                         // uniform addr -> broadcast
        c0[q] += wv * a[j];
        c1[q] += wv * b[j];
      }
    }
  }

  // ---- Phase B: recurrence, h overwrites c; 2 independent chains -------
  float ldp0 = 1.f, ldp1 = 1.f;
  #pragma unroll
  for (int f = 0; f < NF_F; ++f) {
    f4 a0 = (f4)(0.f), a1 = (f4)(0.f);
    #pragma unroll
    for (int q = 0; q < (f + 3) / 4; ++q) {    // zero-padded triangular
      f4 g = gt4[f * (NF_F / 4) + q];
      a0 += g * c0[q];
      a1 += g * c1[q];
    }
    float b_f = sp[L_BS + f], wuh_f = sp[L_WUH + f];
    float s0 = c0[f / 4][f % 4] + b_f + ((a0.x + a0.y) + (a0.z + a0.w));
    float s1 = c1[f / 4][f % 4] + b_f + ((a1.x + a1.y) + (a1.z + a1.w));
    float h0 = fast_tanh(s0), h1 = fast_tanh(s1);
    ldp0 *= fmaf(fmaf(-h0, h0, 1.f), wuh_f, 1.f);
    ldp1 *= fmaf(fmaf(-h1, h1, 1.f), wuh_f, 1.f);
    c0[f / 4][f % 4] = h0;                     // h replaces c
    c1[f / 4][f % 4] = h1;
  }

  // ---- Phase C: z = x + Uhat^T h (LDS broadcast uhat) ------------------
  f4* __restrict__ ov0 = reinterpret_cast<f4*>(out_z + (size_t)r0 * NF_D);
  f4* __restrict__ ov1 = reinterpret_cast<f4*>(out_z + (size_t)r1 * NF_D);

  #pragma unroll 2
  for (int dc = 0; dc < NF_D / 4; ++dc) {
    f4 z0 = xv0[dc], z1 = xv1[dc];             // x re-read: L2/LLC-resident
    #pragma unroll
    for (int f = 0; f < NF_F; ++f) {
      f4 u = uh4[f * (NF_D / 4) + dc];         // uniform addr -> broadcast
      z0 += u * c0[f / 4][f % 4];
      z1 += u * c1[f / 4][f % 4];
    }
    if (ok0) ov0[dc] = z0;
    if (ok1) ov1[dc] = z1;
  }
  if (ok0) out_ld[t0] = __builtin_amdgcn_logf(fabsf(ldp0)) * 0.6931471805599453f;
  if (ok1) out_ld[t1] = __builtin_amdgcn_logf(fabsf(ldp1)) * 0.6931471805599453f;
}

extern "C" void kernel_launch(void* const* d_in, const int* in_sizes, int n_in,
                              void* d_out, int out_size, void* d_ws, size_t ws_size,
                              hipStream_t stream) {
  const float* x    = (const float*)d_in[0];
  const float* us   = (const float*)d_in[1];
  const float* ws_p = (const float*)d_in[2];
  const float* bs   = (const float*)d_in[3];
  const int B = in_sizes[0] / NF_D;

  float* wsbuf = (float*)d_ws;   // L_TOT floats ~ 20.7 KB
  float* out   = (float*)d_out;  // z [B*D] then sum_log_det [B]

  nf_precompute<<<1, 256, 0, stream>>>(us, ws_p, wsbuf);
  const int block = 256;
  const int rows_per_block = block * 2;
  const int grid = (B + rows_per_block - 1) / rows_per_block;
  nf_main<<<grid, block, 0, stream>>>(x, bs, wsbuf,
                                      out, out + (size_t)B * NF_D, B);
}

// Round 9
// 99.674 us; speedup vs baseline: 4.1359x; 2.1571x over previous
//
#include <hip/hip_runtime.h>
#include <math.h>

// Planar normalizing flow, B=524288 rows, D=64, F=32.
// Plain z-carry form (round 4 = 99us, best so far), fixed for its two
// measured losses:
//  - AGPR-parking of z[16]f4 (VGPR_Count=40, accvgpr moves ~2x VALU work):
//    __launch_bounds__(256, 2) gives a ~256-reg budget so z stays in
//    arch VGPRs. (Round 3's (256,2) failure was confounded: named z0..z15
//    temps + nontemporal stores + unroll-2; all absent here.)
//  - 47MB spill from unroll-2 at a tight budget: now there is headroom.
// Params (w[f][*], uhat[f][*]: 16KB/row) stay on the wave-uniform s_load
// path (r5 proved per-lane VMEM params 4x worse; r8 proved LDS params
// LDS-pipe bound since uniform ds_reads don't amortize across waves).
// unroll-2 on the f-loop lets flow f+1's 8 s_loads prefetch under flow f's
// ~140cyc of pk-FMA compute; 8 waves/CU TLP covers the remainder.

#define NF_D 64
#define NF_F 32

typedef float f4 __attribute__((ext_vector_type(4)));

// --- Step 1: precompute u_hat[F][D] and wuh[F] = w . u_hat ---------------
__global__ void nf_precompute(const float* __restrict__ us,
                              const float* __restrict__ ws,
                              float* __restrict__ uhat,
                              float* __restrict__ wuh) {
  int f = threadIdx.x;
  if (f >= NF_F) return;
  const float* u = us + f * NF_D;
  const float* w = ws + f * NF_D;
  float wu = 0.f, n2 = 0.f;
  for (int d = 0; d < NF_D; ++d) {
    wu = fmaf(u[d], w[d], wu);
    n2 = fmaf(w[d], w[d], n2);
  }
  float sp = fmaxf(wu, 0.f) + log1pf(expf(-fabsf(wu)));  // softplus
  float coef = (sp - 1.f - wu) / sqrtf(n2);   // u_hat = u + coef * w
  for (int d = 0; d < NF_D; ++d)
    uhat[f * NF_D + d] = fmaf(coef, w[d], u[d]);
  wuh[f] = fmaf(coef, n2, wu);                // w . u_hat
}

// tanh(x) = 1 - 2/(e^{2x}+1); hardware exp2/rcp; saturates to +-1.
__device__ __forceinline__ float fast_tanh(float x) {
  float e = __builtin_amdgcn_exp2f(x * 2.885390081777927f); // 2*log2(e)
  return 1.f - 2.f * __builtin_amdgcn_rcpf(e + 1.f);
}

// --- Step 2: main flow, one thread per row, 256-reg budget ---------------
__global__ __launch_bounds__(256, 2) void nf_main(
    const float* __restrict__ x,
    const float* __restrict__ ws,
    const float* __restrict__ bs,
    const float* __restrict__ uhat,
    const float* __restrict__ wuh,
    float* __restrict__ out_z,
    float* __restrict__ out_ld,
    int B) {
  int row = blockIdx.x * blockDim.x + threadIdx.x;
  if (row >= B) return;

  const f4* __restrict__ xv =
      reinterpret_cast<const f4*>(x + (size_t)row * NF_D);
  f4 z[NF_D / 4];
  #pragma unroll
  for (int i = 0; i < NF_D / 4; ++i) z[i] = xv[i];

  float ldp = 1.f;                       // product of (1 + h' * w.u_hat)
  #pragma unroll 2
  for (int f = 0; f < NF_F; ++f) {       // f wave-uniform -> s_load params
    const f4* __restrict__ wq = reinterpret_cast<const f4*>(ws + f * NF_D);
    const f4* __restrict__ uq = reinterpret_cast<const f4*>(uhat + f * NF_D);

    // two f4 accumulators: 8-deep dep chains, 8-wide ILP
    f4 acc0 = (f4)(0.f), acc1 = (f4)(0.f);
    #pragma unroll
    for (int i = 0; i < NF_D / 8; ++i) {
      acc0 += z[2 * i]     * wq[2 * i];      // v_pk_fma_f32
      acc1 += z[2 * i + 1] * wq[2 * i + 1];
    }
    f4 acc = acc0 + acc1;
    float lin = ((acc.x + acc.y) + (acc.z + acc.w)) + bs[f];
    float h = fast_tanh(lin);

    #pragma unroll
    for (int i = 0; i < NF_D / 4; ++i)
      z[i] += uq[i] * h;                     // v_pk_fma_f32

    float hp = fmaf(-h, h, 1.f);             // 1 - h^2
    ldp *= fmaf(hp, wuh[f], 1.f);            // 1 + h'*(w.u_hat)
  }

  f4* __restrict__ ov = reinterpret_cast<f4*>(out_z + (size_t)row * NF_D);
  #pragma unroll
  for (int i = 0; i < NF_D / 4; ++i) ov[i] = z[i];
  // sum log|t_f| = log|prod t_f|; t in [~0.6,1.1] so the product is safe.
  out_ld[row] = __builtin_amdgcn_logf(fabsf(ldp)) * 0.6931471805599453f;
}

extern "C" void kernel_launch(void* const* d_in, const int* in_sizes, int n_in,
                              void* d_out, int out_size, void* d_ws, size_t ws_size,
                              hipStream_t stream) {
  const float* x    = (const float*)d_in[0];
  const float* us   = (const float*)d_in[1];
  const float* ws_p = (const float*)d_in[2];
  const float* bs   = (const float*)d_in[3];
  const int B = in_sizes[0] / NF_D;

  float* uhat = (float*)d_ws;            // F*D floats
  float* wuh  = uhat + NF_F * NF_D;      // F floats
  float* out  = (float*)d_out;           // z [B*D] then sum_log_det [B]

  nf_precompute<<<1, 64, 0, stream>>>(us, ws_p, uhat, wuh);
  const int block = 256;
  const int grid = (B + block - 1) / block;
  nf_main<<<grid, block, 0, stream>>>(x, ws_p, bs, uhat, wuh,
                                      out, out + (size_t)B * NF_D, B);
}